// Round 3
// baseline (8126.499 us; speedup 1.0000x reference)
//
#include <hip/hip_runtime.h>
#include <hip/hip_bf16.h>
#include <stdint.h>

// ---------------------------------------------------------------------------
// DiffusionModel: 100 fused steps of x <- x + B*(x@Wx + t*csum + b) + s*noise
// R8 (on R7's 64-row / nt-split / 1-barrier structure):
//  - depth-8 rolling W prefetch (bf[8], 32 VGPR): R7's FETCH=12GB showed the
//    blob misses L2 essentially every read; depth-2 cover (~60cyc) << miss
//    latency (300-900cyc) -> sweeps stalled on vmcnt. Depth 8 => half of each
//    sweep's chunks are issued a whole update-phase early, the rest ~8 iters.
//  - sched_barrier(0) per element-pair in the update: caps live set to 2 RNG
//    chains (anti AGPR-shuffle; R6 showed the pressure failure mode). 2
//    chains x 4 waves/SIMD still saturate VALU issue.
//  - xs XOR swizzle (byte ^= 32 iff row bit3): ds_write_b16 4-way conflicts
//    (SQ_LDS_BANK_CONFLICT 4.19e8) -> 2-way (free); reads stay 2-way; XOR
//    folds into per-mt read base (zero cost), 1 v_xor per write.
//  - rotl via __builtin_rotateleft32 -> guaranteed v_alignbit_b32.
//
// REGISTER MODEL (R2-R7 measured): budget = 512/launch_bounds_arg2 = 128
// (VGPR+AGPR unified). Arch side worst (sweep): bf 32 + af 4 + addr ~16 +
// temps ~8 = ~60 <= 64; AGPR: xr 32 + acc 16 = 48. Spill symptom to watch:
// WRITE_SIZE >> 0.4GB (R6: 3.56GB phantom scratch writes).
// ---------------------------------------------------------------------------

typedef __attribute__((ext_vector_type(8))) short short8;
typedef __attribute__((ext_vector_type(4))) float f32x4;

#define XS_STRIDE 520          // bf16 elems per x-row in LDS (512+8 pad)
#define NSTEP 100

// Threefry-2x32, 20 rounds, exactly as jax._src.prng.threefry2x32
__device__ __forceinline__ void tf_rounds(uint32_t k0, uint32_t k1, uint32_t k2,
                                          uint32_t& a, uint32_t& b) {
  a += k0; b += k1;
#define TFR(r) { a += b; b = __builtin_rotateleft32(b, (r)); b ^= a; }
  TFR(13) TFR(15) TFR(26) TFR(6)   a += k1; b += k2 + 1u;
  TFR(17) TFR(29) TFR(16) TFR(24)  a += k2; b += k0 + 2u;
  TFR(13) TFR(15) TFR(26) TFR(6)   a += k0; b += k1 + 3u;
  TFR(17) TFR(29) TFR(16) TFR(24)  a += k1; b += k2 + 4u;
  TFR(13) TFR(15) TFR(26) TFR(6)   a += k2; b += k0 + 5u;
#undef TFR
}

// bits -> uniform[-0.99999994, 1) -> sqrt(2)*erfinv(u)  (XLA/Giles erfinv).
// Bit-identical to R5-R7 (RNG must match the JAX reference).
__device__ __forceinline__ float gauss_from_bits(uint32_t bits) {
  const float lo = __uint_as_float(0xBF7FFFFFu);   // nextafter(-1,0)
  float f = __uint_as_float((bits >> 9) | 0x3F800000u) - 1.0f;  // [0,1)
  float u = fmaxf(lo, fmaf(f, 2.0f, lo));
  float om = fmaf(u, -u, 1.0f);                    // 1-u^2 > 0
  float L = __log2f(om);                           // w = -ln2 * L
  float p;
  if (__builtin_expect(L > -7.2134752f, 1)) {      // w < 5
    float z = fmaf(-0.69314718f, L, -2.5f);        // w - 2.5
    p =            2.81022636e-08f;
    p = fmaf(p, z, 3.43273939e-07f);
    p = fmaf(p, z, -3.5233877e-06f);
    p = fmaf(p, z, -4.39150654e-06f);
    p = fmaf(p, z, 0.00021858087f);
    p = fmaf(p, z, -0.00125372503f);
    p = fmaf(p, z, -0.00417768164f);
    p = fmaf(p, z, 0.246640727f);
    p = fmaf(p, z, 1.50140941f);
  } else {
    float z = sqrtf(-0.69314718f * L) - 3.0f;
    p =            -0.000200214257f;
    p = fmaf(p, z, 0.000100950558f);
    p = fmaf(p, z, 0.00134934322f);
    p = fmaf(p, z, -0.00367342844f);
    p = fmaf(p, z, 0.00573950773f);
    p = fmaf(p, z, -0.0076224613f);
    p = fmaf(p, z, 0.00943887047f);
    p = fmaf(p, z, 1.00167406f);
    p = fmaf(p, z, 2.83297682f);
  }
  return 1.41421356f * (p * u);   // sqrt(2) * erfinv(u)
}

// f32 -> bf16 RNE (bit trick) — prep kernel only
__device__ __forceinline__ uint16_t f2bf(float f) {
  uint32_t u = __float_as_uint(f);
  u += 0x7FFFu + ((u >> 16) & 1u);
  return (uint16_t)(u >> 16);
}

// packed pair f32x2 -> bf16x2 (v_cvt_pk_bf16_f32; RNE == bit-trick on
// normal values, which is all x ever is here)
__device__ __forceinline__ uint32_t f2bf_pk(float lo, float hi) {
  union { __hip_bfloat162 h; uint32_t u; } cv;
  cv.h = __float22bfloat162_rn(make_float2(lo, hi));
  return cv.u;
}

// --------------------------------------------------------------------------
// Pre-pass 1: Wx (rows 0..511 of W) -> bf16 blob, UNPADDED [c][n][32]:
// chunk c holds k in [32c,32c+32); B-frag for (c,n,q) = 16B at n*64+q*16 B.
// --------------------------------------------------------------------------
__global__ void prep_w_kernel(const float* __restrict__ W, uint16_t* __restrict__ blob) {
  int id = blockIdx.x * 256 + threadIdx.x;
  if (id >= 512 * 512) return;
  int k = id >> 9;        // feature (K) index
  int n = id & 511;       // output col
  float v = W[k * 512 + n];
  int c = k >> 5, kk = k & 31;
  blob[c * 16384 + n * 32 + kk] = f2bf(v);
}

// Pre-pass 2: csum[n] = sum_j W[512+j][n]  (rank-1 t-embedding part)
__global__ void prep_csum_kernel(const float* __restrict__ W, float* __restrict__ csum) {
  int n = blockIdx.x * 256 + threadIdx.x;
  if (n >= 512) return;
  float s = 0.0f;
  for (int j = 0; j < 512; ++j) s += W[(512 + j) * 512 + n];
  csum[n] = s;
}

// --------------------------------------------------------------------------
// Main fused kernel. MFMA 16x16x32 bf16: A[m=lane&15][k=q*8+j] (from xs),
// B[k][n=lane&15] (direct global 16B coalesced load), C row=4q+reg.
// Block owns rows [64b, 64b+64): mt in 0..3; wave w covers cols [32w,32w+32):
// nt in {0,1}, two sequential K-sweeps. xs double-buffered, 1 barrier/step.
//
// xs swizzle: logical byte A = row*1040 + col*2; stored at A ^ ((row&8)<<2).
// Reads (b128, 16B blocks at A%32 in {0,16}): XOR granule is 32B -> blocks
// stay contiguous; (l15&8)<<2 folds into the per-mt base (adding c*64 never
// touches bits <6). Writes: (row&8)=8 iff q>=2 -> swzw=(q&2)<<4 per-thread.
// --------------------------------------------------------------------------
__global__ __launch_bounds__(1024, 4) void diffuse_kernel(
    const float* __restrict__ x0, const uint16_t* __restrict__ wblob,
    const float* __restrict__ csum, const float* __restrict__ bvec,
    float* __restrict__ out) {
  __shared__ alignas(16) uint16_t xs[2][64 * XS_STRIDE];  // 2 x 66560 B
  __shared__ alignas(8) float2 cb[512];                   // 4096 B {csum, bias}

  const int tid = threadIdx.x;
  const int l15 = tid & 15;
  const int q   = (tid >> 4) & 3;
  const int wv  = tid >> 6;        // wave 0..15
  const int blk = blockIdx.x;      // 0..511
  const int swzw = (q & 2) << 4;   // write-side xs swizzle (32 iff q>=2)

  if (tid < 512) cb[tid] = make_float2(csum[tid], bvec[tid]);

  int ncol[2];
#pragma unroll
  for (int nt = 0; nt < 2; ++nt)
    ncol[nt] = wv * 32 + nt * 16 + l15;

  // per-mt swizzled read base: ((row*520 + q*8)*2) ^ ((l15&8)<<2)
  int rbase[4];
#pragma unroll
  for (int mt = 0; mt < 4; ++mt)
    rbase[mt] = (((mt * 16 + l15) * XS_STRIDE + q * 8) * 2) ^ ((l15 & 8) << 2);

  // fp32 master of x, C-layout: (mt,nt)[j] = local row 16mt+4q+j, col ncol[nt]
  f32x4 xr[4][2];
#pragma unroll
  for (int mt = 0; mt < 4; ++mt)
#pragma unroll
    for (int j = 0; j < 4; ++j) {
      int gr = blk * 64 + mt * 16 + q * 4 + j;
#pragma unroll
      for (int nt = 0; nt < 2; ++nt)
        xr[mt][nt][j] = x0[gr * 512 + ncol[nt]];
    }

  // initial bf16 image into buffer 0 (packed pairs: rows m, m+1; swizzled)
#pragma unroll
  for (int mt = 0; mt < 4; ++mt)
#pragma unroll
    for (int nt = 0; nt < 2; ++nt)
#pragma unroll
      for (int jj = 0; jj < 2; ++jj) {
        int m = mt * 16 + q * 4 + jj * 2;
        uint32_t pk = f2bf_pk(xr[mt][nt][jj * 2], xr[mt][nt][jj * 2 + 1]);
        int a0 = ((m * XS_STRIDE + ncol[nt]) * 2) ^ swzw;
        int a1 = (((m + 1) * XS_STRIDE + ncol[nt]) * 2) ^ swzw;
        *(uint16_t*)((char*)&xs[0][0] + a0) = (uint16_t)pk;
        *(uint16_t*)((char*)&xs[0][0] + a1) = (uint16_t)(pk >> 16);
      }

  const float sq2b = sqrtf(0.02f);   // sqrt(2*beta)
  const f32x4 vzero = {0.0f, 0.0f, 0.0f, 0.0f};

  // W fragment bases per column half; chunk addresses are t-invariant: the
  // prefetch stream is perfectly periodic (nt0 c0..15, nt1 c0..15, repeat).
  const uint16_t* wb[2] = {wblob + ncol[0] * 32 + q * 8,
                           wblob + ncol[1] * 32 + q * 8};
  // depth-8 rolling prefetch: bf[0..7] = next 8 positions of the stream
  short8 bf[8];
#pragma unroll
  for (int i = 0; i < 8; ++i)
    bf[i] = *(const short8*)(wb[0] + i * 16384);

  __syncthreads();   // init image + cb visible to all waves
  const float2 cbv0 = cb[ncol[0]];
  const float2 cbv1 = cb[ncol[1]];

  for (int t = 0; t < NSTEP; ++t) {
    const uint16_t* xsc = xs[t & 1];
    uint16_t* xsn = xs[(t + 1) & 1];

    // key_t = fold_in(key(42), t) = threefry((0,42),(0,t))  [uniform -> SALU]
    uint32_t kt0 = 0u, kt1 = (uint32_t)t;
    tf_rounds(0u, 42u, 42u ^ 0x1BD11BDAu, kt0, kt1);
    const uint32_t kk2 = kt0 ^ kt1 ^ 0x1BD11BDAu;
    const float tf = (float)t;

#pragma unroll
    for (int nt = 0; nt < 2; ++nt) {
      f32x4 acc[4];
#pragma unroll
      for (int mt = 0; mt < 4; ++mt) acc[mt] = vzero;

      // ---- K sweep: consume bf[0] (issued 8 positions ago), issue position
      //      c+8 (wraps into the next sweep; update phase covers the wrap) --
#pragma unroll
      for (int c = 0; c < 16; ++c) {
        const uint16_t* pp = (c < 8) ? (wb[nt] + (c + 8) * 16384)
                                     : (wb[nt ^ 1] + (c - 8) * 16384);
        short8 bnew = *(const short8*)pp;
#pragma unroll
        for (int mt = 0; mt < 4; ++mt) {
          short8 af = *(const short8*)((const char*)xsc + rbase[mt] + c * 64);
          acc[mt] = __builtin_amdgcn_mfma_f32_16x16x32_bf16(af, bf[0], acc[mt], 0, 0, 0);
        }
#pragma unroll
        for (int i = 0; i < 7; ++i) bf[i] = bf[i + 1];
        bf[7] = bnew;
      }

      // ---- noise + update for this half (VALU only, barrier-free).
      //      sched_barrier(0) per pair: caps live set to 2 RNG chains ----
      const float2 cbv = nt ? cbv1 : cbv0;
      const float tc = fmaf(tf, cbv.x, cbv.y);
#pragma unroll
      for (int mt = 0; mt < 4; ++mt) {
        const uint32_t ebase =
            (uint32_t)((blk * 64 + mt * 16 + q * 4) * 512 + ncol[nt]);
#pragma unroll
        for (int jj = 0; jj < 2; ++jj) {
          float xv[2];
#pragma unroll
          for (int r = 0; r < 2; ++r) {
            int j = jj * 2 + r;
            float sc = acc[mt][j] + tc;
            float v = fmaf(0.01f, sc, xr[mt][nt][j]);   // x + B*score
            uint32_t a = 0u, b = ebase + (uint32_t)(j * 512);
            tf_rounds(kt0, kt1, kk2, a, b);
            v = fmaf(sq2b, gauss_from_bits(a ^ b), v);  // + s*noise
            xr[mt][nt][j] = v;
            xv[r] = v;
          }
          // next-step image (other buffer; swizzled). t=99's writes are dead
          // but harmless (no barrier after; xs[0] never read again).
          int m = mt * 16 + q * 4 + jj * 2;
          uint32_t pk = f2bf_pk(xv[0], xv[1]);
          int a0 = ((m * XS_STRIDE + ncol[nt]) * 2) ^ swzw;
          int a1 = (((m + 1) * XS_STRIDE + ncol[nt]) * 2) ^ swzw;
          *(uint16_t*)((char*)xsn + a0) = (uint16_t)pk;
          *(uint16_t*)((char*)xsn + a1) = (uint16_t)(pk >> 16);
          __builtin_amdgcn_sched_barrier(0);
        }
      }
    }

    if (t + 1 < NSTEP) __syncthreads();
  }

  // final store (fp32)
#pragma unroll
  for (int mt = 0; mt < 4; ++mt)
#pragma unroll
    for (int j = 0; j < 4; ++j) {
      int gr = blk * 64 + mt * 16 + q * 4 + j;
#pragma unroll
      for (int nt = 0; nt < 2; ++nt)
        out[gr * 512 + ncol[nt]] = xr[mt][nt][j];
    }
}

extern "C" void kernel_launch(void* const* d_in, const int* in_sizes, int n_in,
                              void* d_out, int out_size, void* d_ws, size_t ws_size,
                              hipStream_t stream) {
  const float* x0 = (const float*)d_in[0];   // (32768, 512)
  const float* W  = (const float*)d_in[1];   // (1024, 512)
  const float* bv = (const float*)d_in[2];   // (512,)
  float* out = (float*)d_out;

  uint16_t* blob = (uint16_t*)d_ws;                     // 512 KB bf16 W-blob
  float* csum = (float*)((char*)d_ws + 16 * 16384 * 2); // +2 KB

  prep_w_kernel<<<dim3(1024), dim3(256), 0, stream>>>(W, blob);
  prep_csum_kernel<<<dim3(2), dim3(256), 0, stream>>>(W, csum);
  diffuse_kernel<<<dim3(512), dim3(1024), 0, stream>>>(x0, blob, csum, bv, out);
}

// Round 5
// 5346.216 us; speedup vs baseline: 1.5200x; 1.5200x over previous
//
#include <hip/hip_runtime.h>
#include <hip/hip_bf16.h>
#include <stdint.h>

// ---------------------------------------------------------------------------
// DiffusionModel: 100 fused steps of x <- x + B*(x@Wx + t*csum + b) + s*noise
// R9 (resubmit; previous round failed on container infra, not the kernel)
// = R7 structure (64 rows/block, nt-split sweeps, depth-2 W prefetch,
// double-buffered xs, 1 barrier/step) + RNG FOLDED INTO THE K-SWEEP:
// sweep iteration c computes threefry+erfinv for element (mt=c>>2, j=c&3)
// and does xr += s*noise in place. Mechanism: R7/R8 counters showed the
// sweep is W-latency-stalled (VALU ~0) while the update phase is pure VALU
// (memory ~0), run back-to-back -> 34% idle. Interleaving fills the vmcnt
// stall slots with RNG work and gives the depth-2 prefetch ~200 instr of
// cover. Update phase shrinks to 2 fma + pack + ds_write per element.
// R8 post-mortem: sched_barrier(0) pinning = m141 failure (-24%); depth-8
// bf[] = +pressure, FETCH up; xs XOR swizzle = provably no-op on the 2-way
// b128 read conflict (16 lanes x 4 banks > 32 banks is a structural floor,
// ~2.6% of runtime). All three reverted.
//
// REGISTER MODEL (R2-R8 measured): budget = 512/launch_bounds_arg2 = 128
// (VGPR+AGPR unified; pool 512/SIMD, 4 waves/SIMD resident). Arch side in
// sweep: bf 12 + af 4 + 1-2 RNG chains ~10 + addr ~16 = ~45 <= 64; AGPR:
// xr 32 + acc 16 = 48. Spill symptom: WRITE_SIZE >> 0.4 GB (R6: 3.56 GB).
// Noise reorder note: x_next = (x + s*n) + B*score (ref is (x+B*s)+s*n);
// ~ulp/step difference, harmless at 0.5 tolerance.
// ---------------------------------------------------------------------------

typedef __attribute__((ext_vector_type(8))) short short8;
typedef __attribute__((ext_vector_type(4))) float f32x4;

#define XS_STRIDE 520          // bf16 elems per x-row in LDS (512+8 pad)
#define NSTEP 100

// Threefry-2x32, 20 rounds, exactly as jax._src.prng.threefry2x32
__device__ __forceinline__ void tf_rounds(uint32_t k0, uint32_t k1, uint32_t k2,
                                          uint32_t& a, uint32_t& b) {
  a += k0; b += k1;
#define TFR(r) { a += b; b = __builtin_rotateleft32(b, (r)); b ^= a; }
  TFR(13) TFR(15) TFR(26) TFR(6)   a += k1; b += k2 + 1u;
  TFR(17) TFR(29) TFR(16) TFR(24)  a += k2; b += k0 + 2u;
  TFR(13) TFR(15) TFR(26) TFR(6)   a += k0; b += k1 + 3u;
  TFR(17) TFR(29) TFR(16) TFR(24)  a += k1; b += k2 + 4u;
  TFR(13) TFR(15) TFR(26) TFR(6)   a += k2; b += k0 + 5u;
#undef TFR
}

// bits -> uniform[-0.99999994, 1) -> sqrt(2)*erfinv(u)  (XLA/Giles erfinv).
// Bit-identical to R5-R8 (RNG must match the JAX reference).
__device__ __forceinline__ float gauss_from_bits(uint32_t bits) {
  const float lo = __uint_as_float(0xBF7FFFFFu);   // nextafter(-1,0)
  float f = __uint_as_float((bits >> 9) | 0x3F800000u) - 1.0f;  // [0,1)
  float u = fmaxf(lo, fmaf(f, 2.0f, lo));
  float om = fmaf(u, -u, 1.0f);                    // 1-u^2 > 0
  float L = __log2f(om);                           // w = -ln2 * L
  float p;
  if (__builtin_expect(L > -7.2134752f, 1)) {      // w < 5
    float z = fmaf(-0.69314718f, L, -2.5f);        // w - 2.5
    p =            2.81022636e-08f;
    p = fmaf(p, z, 3.43273939e-07f);
    p = fmaf(p, z, -3.5233877e-06f);
    p = fmaf(p, z, -4.39150654e-06f);
    p = fmaf(p, z, 0.00021858087f);
    p = fmaf(p, z, -0.00125372503f);
    p = fmaf(p, z, -0.00417768164f);
    p = fmaf(p, z, 0.246640727f);
    p = fmaf(p, z, 1.50140941f);
  } else {
    float z = sqrtf(-0.69314718f * L) - 3.0f;
    p =            -0.000200214257f;
    p = fmaf(p, z, 0.000100950558f);
    p = fmaf(p, z, 0.00134934322f);
    p = fmaf(p, z, -0.00367342844f);
    p = fmaf(p, z, 0.00573950773f);
    p = fmaf(p, z, -0.0076224613f);
    p = fmaf(p, z, 0.00943887047f);
    p = fmaf(p, z, 1.00167406f);
    p = fmaf(p, z, 2.83297682f);
  }
  return 1.41421356f * (p * u);   // sqrt(2) * erfinv(u)
}

// f32 -> bf16 RNE (bit trick) — prep kernel only
__device__ __forceinline__ uint16_t f2bf(float f) {
  uint32_t u = __float_as_uint(f);
  u += 0x7FFFu + ((u >> 16) & 1u);
  return (uint16_t)(u >> 16);
}

// packed pair f32x2 -> bf16x2 (v_cvt_pk_bf16_f32; RNE == bit-trick on
// normal values, which is all x ever is here)
__device__ __forceinline__ uint32_t f2bf_pk(float lo, float hi) {
  union { __hip_bfloat162 h; uint32_t u; } cv;
  cv.h = __float22bfloat162_rn(make_float2(lo, hi));
  return cv.u;
}

// --------------------------------------------------------------------------
// Pre-pass 1: Wx (rows 0..511 of W) -> bf16 blob, UNPADDED [c][n][32]:
// chunk c holds k in [32c,32c+32); B-frag for (c,n,q) = 16B at n*64+q*16 B.
// --------------------------------------------------------------------------
__global__ void prep_w_kernel(const float* __restrict__ W, uint16_t* __restrict__ blob) {
  int id = blockIdx.x * 256 + threadIdx.x;
  if (id >= 512 * 512) return;
  int k = id >> 9;        // feature (K) index
  int n = id & 511;       // output col
  float v = W[k * 512 + n];
  int c = k >> 5, kk = k & 31;
  blob[c * 16384 + n * 32 + kk] = f2bf(v);
}

// Pre-pass 2: csum[n] = sum_j W[512+j][n]  (rank-1 t-embedding part)
__global__ void prep_csum_kernel(const float* __restrict__ W, float* __restrict__ csum) {
  int n = blockIdx.x * 256 + threadIdx.x;
  if (n >= 512) return;
  float s = 0.0f;
  for (int j = 0; j < 512; ++j) s += W[(512 + j) * 512 + n];
  csum[n] = s;
}

// --------------------------------------------------------------------------
// Main fused kernel. MFMA 16x16x32 bf16: A[m=lane&15][k=q*8+j] (from xs),
// B[k][n=lane&15] (direct global 16B coalesced load), C row=4q+reg.
// Block owns rows [64b, 64b+64): mt in 0..3; wave w covers cols [32w,32w+32):
// nt in {0,1}, two sequential K-sweeps with RNG interleaved.
// xs double-buffered, 1 barrier/step.
// --------------------------------------------------------------------------
__global__ __launch_bounds__(1024, 4) void diffuse_kernel(
    const float* __restrict__ x0, const uint16_t* __restrict__ wblob,
    const float* __restrict__ csum, const float* __restrict__ bvec,
    float* __restrict__ out) {
  __shared__ alignas(16) uint16_t xs[2][64 * XS_STRIDE];  // 2 x 66560 B
  __shared__ alignas(8) float2 cb[512];                   // 4096 B {csum, bias}

  const int tid = threadIdx.x;
  const int l15 = tid & 15;
  const int q   = (tid >> 4) & 3;
  const int wv  = tid >> 6;        // wave 0..15
  const int blk = blockIdx.x;      // 0..511

  if (tid < 512) cb[tid] = make_float2(csum[tid], bvec[tid]);

  int ncol[2];
#pragma unroll
  for (int nt = 0; nt < 2; ++nt)
    ncol[nt] = wv * 32 + nt * 16 + l15;

  // fp32 master of x, C-layout: (mt,nt)[j] = local row 16mt+4q+j, col ncol[nt]
  f32x4 xr[4][2];
#pragma unroll
  for (int mt = 0; mt < 4; ++mt)
#pragma unroll
    for (int j = 0; j < 4; ++j) {
      int gr = blk * 64 + mt * 16 + q * 4 + j;
#pragma unroll
      for (int nt = 0; nt < 2; ++nt)
        xr[mt][nt][j] = x0[gr * 512 + ncol[nt]];
    }

  // initial bf16 image into buffer 0 (packed pairs: rows m, m+1)
#pragma unroll
  for (int mt = 0; mt < 4; ++mt)
#pragma unroll
    for (int nt = 0; nt < 2; ++nt)
#pragma unroll
      for (int jj = 0; jj < 2; ++jj) {
        int m = mt * 16 + q * 4 + jj * 2;
        uint32_t pk = f2bf_pk(xr[mt][nt][jj * 2], xr[mt][nt][jj * 2 + 1]);
        xs[0][m * XS_STRIDE + ncol[nt]] = (uint16_t)pk;
        xs[0][(m + 1) * XS_STRIDE + ncol[nt]] = (uint16_t)(pk >> 16);
      }

  const float sq2b = sqrtf(0.02f);   // sqrt(2*beta)
  const f32x4 vzero = {0.0f, 0.0f, 0.0f, 0.0f};

  // W fragment bases per column half; chunk addresses are t-invariant: the
  // prefetch stream is perfectly periodic (nt0 c0..15, nt1 c0..15, repeat).
  const uint16_t* wb[2] = {wblob + ncol[0] * 32 + q * 8,
                           wblob + ncol[1] * 32 + q * 8};
  // rolling depth-2 prefetch: bf0/bf1 = chunks 0,1 of the upcoming sweep (nt=0)
  short8 bf0 = *(const short8*)(wb[0]);
  short8 bf1 = *(const short8*)(wb[0] + 16384);

  __syncthreads();   // init image + cb visible to all waves
  const float2 cbv0 = cb[ncol[0]];
  const float2 cbv1 = cb[ncol[1]];

  for (int t = 0; t < NSTEP; ++t) {
    const uint16_t* xsc = xs[t & 1];
    uint16_t* xsn = xs[(t + 1) & 1];

    // key_t = fold_in(key(42), t) = threefry((0,42),(0,t))  [uniform -> SALU]
    uint32_t kt0 = 0u, kt1 = (uint32_t)t;
    tf_rounds(0u, 42u, 42u ^ 0x1BD11BDAu, kt0, kt1);
    const uint32_t kk2 = kt0 ^ kt1 ^ 0x1BD11BDAu;
    const float tf = (float)t;

#pragma unroll
    for (int nt = 0; nt < 2; ++nt) {
      f32x4 acc[4];
#pragma unroll
      for (int mt = 0; mt < 4; ++mt) acc[mt] = vzero;

      // global element base for this half: row (blk*64 + q*4), col ncol[nt]
      const uint32_t base_e = (uint32_t)((blk * 64 + q * 4) * 512 + ncol[nt]);

      // ---- K sweep with RNG interleave: iteration c does
      //        1 W prefetch (depth-2, wraps into next sweep)
      //        4 ds_read_b128 + 4 MFMA (consume bf0)
      //        threefry+erfinv for element (mt=c>>2, j=c&3); xr += s*noise
      //      The ~100 RNG VALU ops per iteration cover the W-load latency. --
#pragma unroll
      for (int c = 0; c < 16; ++c) {
        const uint16_t* pp = (c < 14) ? (wb[nt] + (c + 2) * 16384)
                                      : (wb[nt ^ 1] + (c - 14) * 16384);
        short8 bf2 = *(const short8*)pp;
#pragma unroll
        for (int mt = 0; mt < 4; ++mt) {
          short8 af = *(const short8*)&xsc[(mt * 16 + l15) * XS_STRIDE + c * 32 + q * 8];
          acc[mt] = __builtin_amdgcn_mfma_f32_16x16x32_bf16(af, bf0, acc[mt], 0, 0, 0);
        }
        {
          const int mt_e = c >> 2, j = c & 3;
          uint32_t a = 0u, b = base_e + (uint32_t)(mt_e * 16 * 512 + j * 512);
          tf_rounds(kt0, kt1, kk2, a, b);
          float n = gauss_from_bits(a ^ b);
          xr[mt_e][nt][j] = fmaf(sq2b, n, xr[mt_e][nt][j]);   // x + s*noise
        }
        bf0 = bf1;
        bf1 = bf2;
      }

      // ---- short update: x += B*(acc + t*csum + b), pack, write image ----
      const float2 cbv = nt ? cbv1 : cbv0;
      const float tc = fmaf(tf, cbv.x, cbv.y);
#pragma unroll
      for (int mt = 0; mt < 4; ++mt) {
#pragma unroll
        for (int j = 0; j < 4; ++j)
          xr[mt][nt][j] = fmaf(0.01f, acc[mt][j] + tc, xr[mt][nt][j]);
        if (t + 1 < NSTEP) {
#pragma unroll
          for (int jj = 0; jj < 2; ++jj) {
            int m = mt * 16 + q * 4 + jj * 2;
            uint32_t pk = f2bf_pk(xr[mt][nt][jj * 2], xr[mt][nt][jj * 2 + 1]);
            xsn[m * XS_STRIDE + ncol[nt]] = (uint16_t)pk;
            xsn[(m + 1) * XS_STRIDE + ncol[nt]] = (uint16_t)(pk >> 16);
          }
        }
      }
    }

    if (t + 1 < NSTEP) __syncthreads();
  }

  // final store (fp32)
#pragma unroll
  for (int mt = 0; mt < 4; ++mt)
#pragma unroll
    for (int j = 0; j < 4; ++j) {
      int gr = blk * 64 + mt * 16 + q * 4 + j;
#pragma unroll
      for (int nt = 0; nt < 2; ++nt)
        out[gr * 512 + ncol[nt]] = xr[mt][nt][j];
    }
}

extern "C" void kernel_launch(void* const* d_in, const int* in_sizes, int n_in,
                              void* d_out, int out_size, void* d_ws, size_t ws_size,
                              hipStream_t stream) {
  const float* x0 = (const float*)d_in[0];   // (32768, 512)
  const float* W  = (const float*)d_in[1];   // (1024, 512)
  const float* bv = (const float*)d_in[2];   // (512,)
  float* out = (float*)d_out;

  uint16_t* blob = (uint16_t*)d_ws;                     // 512 KB bf16 W-blob
  float* csum = (float*)((char*)d_ws + 16 * 16384 * 2); // +2 KB

  prep_w_kernel<<<dim3(1024), dim3(256), 0, stream>>>(W, blob);
  prep_csum_kernel<<<dim3(2), dim3(256), 0, stream>>>(W, csum);
  diffuse_kernel<<<dim3(512), dim3(1024), 0, stream>>>(x0, blob, csum, bv, out);
}